// Round 6
// baseline (470.901 us; speedup 1.0000x reference)
//
#include <hip/hip_runtime.h>
#include <hip/hip_bf16.h>
#include <cstdint>
#include <cstddef>

#define NB 2
#define NSEQ 2048
#define NHEADS 16
#define HD 64
#define DMODEL 1024
#define SCALEF 0.125f

typedef __attribute__((ext_vector_type(4))) float f32x4;
typedef __attribute__((ext_vector_type(8))) short s16x8;

__device__ __forceinline__ unsigned short f2bf(float f) {
  union { float f; unsigned u; } v; v.f = f;
  unsigned u = v.u;
  return (unsigned short)((u + 0x7fffu + ((u >> 16) & 1u)) >> 16);
}
__device__ __forceinline__ float bf2f(unsigned short s) {
  union { unsigned u; float f; } v; v.u = ((unsigned)s) << 16;
  return v.f;
}

// ---------- fp32 -> bf16 straight convert (float4 vectorized) ----------
__global__ void k_convert(const float* __restrict__ in, unsigned short* __restrict__ out, int n4) {
  int i = blockIdx.x * blockDim.x + threadIdx.x;
  if (i >= n4) return;
  float4 v = ((const float4*)in)[i];
  ushort4 o;
  o.x = f2bf(v.x); o.y = f2bf(v.y); o.z = f2bf(v.z); o.w = f2bf(v.w);
  ((ushort4*)out)[i] = o;
}

// ---------- w [K][N] fp32 -> wt [N][K] bf16 (LDS-tiled transpose) ----------
__global__ void k_transpose(const float* __restrict__ w, unsigned short* __restrict__ wt, int K, int N) {
  __shared__ float t[64][65];
  int n0 = blockIdx.x * 64, k0 = blockIdx.y * 64;
  int c = threadIdx.x & 63, rb = threadIdx.x >> 6;
#pragma unroll
  for (int rr = 0; rr < 16; rr++) {
    int k = rb * 16 + rr;
    t[c][k] = w[(size_t)(k0 + k) * N + n0 + c];
  }
  __syncthreads();
#pragma unroll
  for (int rr = 0; rr < 16; rr++) {
    int n = rb * 16 + rr;
    wt[(size_t)(n0 + n) * K + k0 + c] = f2bf(t[n][c]);
  }
}

// ---------- bf16 MFMA GEMM: C[M][N] = A[M][K] @ Bt[N][K]^T (+bias) ----------
#define GLD16(gp, lp) __builtin_amdgcn_global_load_lds( \
    (const __attribute__((address_space(1))) unsigned int*)(gp), \
    (__attribute__((address_space(3))) unsigned int*)(lp), 16, 0, 0)

__global__ __launch_bounds__(256) void k_gemm(const unsigned short* __restrict__ A,
                                              const unsigned short* __restrict__ Bt,
                                              float* __restrict__ C,
                                              const float* __restrict__ bias,
                                              int M, int N, int K) {
  __shared__ unsigned short As[128 * 32];
  __shared__ unsigned short Bs[128 * 32];
  const int tid = threadIdx.x;
  const int lane = tid & 63, wid = tid >> 6;
  const int m0 = blockIdx.y * 128, n0 = blockIdx.x * 128;
  const int wr = wid >> 1, wc = wid & 1;
  const int lr = lane >> 2, l4 = lane & 3;
  const int lc = lane & 15, lg = lane >> 4;

  const unsigned short* pa0 = A + (size_t)(m0 + wid * 32 + lr) * K + l4 * 8;
  const unsigned short* pa1 = pa0 + (size_t)16 * K;
  const unsigned short* pb0 = Bt + (size_t)(n0 + wid * 32 + lr) * K + l4 * 8;
  const unsigned short* pb1 = pb0 + (size_t)16 * K;

  f32x4 acc[4][4] = {};

  for (int kt = 0; kt < K; kt += 32) {
    GLD16(pa0 + kt, &As[wid * 1024]);
    GLD16(pa1 + kt, &As[wid * 1024 + 512]);
    GLD16(pb0 + kt, &Bs[wid * 1024]);
    GLD16(pb1 + kt, &Bs[wid * 1024 + 512]);
    __syncthreads();
    s16x8 af[4], bfr[4];
#pragma unroll
    for (int m = 0; m < 4; m++)
      af[m] = *(const s16x8*)&As[(wr * 64 + m * 16 + lc) * 32 + lg * 8];
#pragma unroll
    for (int n = 0; n < 4; n++)
      bfr[n] = *(const s16x8*)&Bs[(wc * 64 + n * 16 + lc) * 32 + lg * 8];
    __builtin_amdgcn_s_setprio(1);
#pragma unroll
    for (int m = 0; m < 4; m++)
#pragma unroll
      for (int n = 0; n < 4; n++)
        acc[m][n] = __builtin_amdgcn_mfma_f32_16x16x32_bf16(af[m], bfr[n], acc[m][n], 0, 0, 0);
    __builtin_amdgcn_s_setprio(0);
    __syncthreads();
  }

  float bv[4] = {0.f, 0.f, 0.f, 0.f};
  if (bias) {
#pragma unroll
    for (int n = 0; n < 4; n++) bv[n] = bias[n0 + wc * 64 + n * 16 + lc];
  }
#pragma unroll
  for (int m = 0; m < 4; m++) {
#pragma unroll
    for (int n = 0; n < 4; n++) {
      int col = n0 + wc * 64 + n * 16 + lc;
#pragma unroll
      for (int r = 0; r < 4; r++) {
        int row = m0 + wr * 64 + m * 16 + lg * 4 + r;
        C[(size_t)row * N + col] = acc[m][n][r] + bv[n];
      }
    }
  }
}

// ---------- RoPE + head-split relayout: [B][N][H*64] f32 -> [B][H][N][64] bf16 ----------
__global__ void k_rope(const float* __restrict__ src, int row_stride,
                       const float* __restrict__ sinp, const float* __restrict__ cosp,
                       unsigned short* __restrict__ dst) {
  int tid = blockIdx.x * 256 + threadIdx.x;
  int p = tid & 31;
  int h = (tid >> 5) & 15;
  int i = (tid >> 9) & 2047;
  int b = tid >> 20;
  int d = p * 2;
  float2 x = *(const float2*)(src + (size_t)(b * NSEQ + i) * row_stride + h * HD + d);
  float o0, o1;
  if (p < 16) {
    size_t sc = (size_t)(b * NSEQ + i) * 32 + d;
    float2 cc = *(const float2*)(cosp + sc);
    float2 ss = *(const float2*)(sinp + sc);
    o0 = x.x * cc.x - x.y * ss.x;
    o1 = x.y * cc.y + x.x * ss.y;
  } else { o0 = x.x; o1 = x.y; }
  size_t off = ((size_t)(b * NHEADS + h) * NSEQ + i) * HD + d;
  unsigned pack = (unsigned)f2bf(o0) | ((unsigned)f2bf(o1) << 16);
  *(unsigned*)(dst + off) = pack;
}

// ---------- v relayout+transpose: kv[B][N][2048](cols 1024..) -> vt [B][H][64][N] bf16 ----------
__global__ void k_vtrans(const float* __restrict__ kv, unsigned short* __restrict__ vt) {
  __shared__ float t[64][65];
  int i0 = blockIdx.x * 64;
  int h = blockIdx.y, b = blockIdx.z;
  int c = threadIdx.x & 63, rb = threadIdx.x >> 6;
#pragma unroll
  for (int rr = 0; rr < 16; rr++) {
    int il = rb * 16 + rr;
    t[il][c] = kv[(size_t)(b * NSEQ + i0 + il) * 2048 + 1024 + h * HD + c];
  }
  __syncthreads();
#pragma unroll
  for (int rr = 0; rr < 16; rr++) {
    int dd = rb * 16 + rr;
    vt[((size_t)(b * NHEADS + h) * HD + dd) * NSEQ + i0 + c] = f2bf(t[c][dd]);
  }
}

// ---------- fused attention v5: stores last (loads never wait behind stores) ----------
// vmcnt retires in-order on CDNA: a load issued after stores can't clear
// s_waitcnt until those stores retire. So the 537 MB attn write phase is moved
// to the END of the kernel (after all PV V-loads); regular (non-NT) stores.
// part[] aliases Sbf rows 0..3, so waves 0-1 stash those rows in regs first.
#define SROWB 2056
__global__ __launch_bounds__(512, 4) void k_attn(const unsigned short* __restrict__ qh,
                                                 const unsigned short* __restrict__ kh,
                                                 const unsigned short* __restrict__ vt,
                                                 float* __restrict__ attn_g,
                                                 unsigned short* __restrict__ ctx) {
  __shared__ unsigned short Sbf[16 * SROWB];   // 65,792 B (bf16 e-values)
  __shared__ float wred[8][16];                // per-wave partial row sums
  __shared__ float invr[16];
  float* part = (float*)Sbf;                   // aliased after stash: [4][16][64]

  const int tid = threadIdx.x;
  const int lane = tid & 63, wid = tid >> 6;   // wid 0..7
  const int i0 = blockIdx.x * 16;
  const int h = blockIdx.y, b = blockIdx.z;
  const int lc = lane & 15, lg = lane >> 4;

  const unsigned short* qb = qh + ((size_t)(b * NHEADS + h) * NSEQ + i0) * HD;
  const unsigned short* kb = kh + (size_t)(b * NHEADS + h) * NSEQ * HD;
  const unsigned short* vb = vt + (size_t)(b * NHEADS + h) * HD * NSEQ;

  // ---- QK^T fused with exp: wave covers cols [wid*256, wid*256+256) ----
  s16x8 aq0 = *(const s16x8*)&qb[lc * HD + lg * 8];
  s16x8 aq1 = *(const s16x8*)&qb[lc * HD + 32 + lg * 8];
  float psum[4] = {0.f, 0.f, 0.f, 0.f};
#pragma unroll 4
  for (int jf = 0; jf < 16; jf++) {
    int j = wid * 256 + jf * 16;
    f32x4 acc = {};
    s16x8 bk0 = *(const s16x8*)&kb[(size_t)(j + lc) * HD + lg * 8];
    s16x8 bk1 = *(const s16x8*)&kb[(size_t)(j + lc) * HD + 32 + lg * 8];
    __builtin_amdgcn_s_setprio(1);
    acc = __builtin_amdgcn_mfma_f32_16x16x32_bf16(aq0, bk0, acc, 0, 0, 0);
    acc = __builtin_amdgcn_mfma_f32_16x16x32_bf16(aq1, bk1, acc, 0, 0, 0);
    __builtin_amdgcn_s_setprio(0);
#pragma unroll
    for (int r = 0; r < 4; r++) {
      float e = __expf(acc[r] * SCALEF);       // no max-sub: |s| bounded ~6
      psum[r] += e;
      Sbf[(size_t)(lg * 4 + r) * SROWB + j + lc] = f2bf(e);
    }
  }
  // row-sum: reduce over the 16 lanes sharing lg, then stage per-wave
#pragma unroll
  for (int off = 1; off <= 8; off <<= 1)
#pragma unroll
    for (int r = 0; r < 4; r++) psum[r] += __shfl_xor(psum[r], off);
  if (lc == 0) {
#pragma unroll
    for (int r = 0; r < 4; r++) wred[wid][lg * 4 + r] = psum[r];
  }
  __syncthreads();

  // ---- per-row inverse sum ----
  {
    const int row16 = tid & 15;
    if (tid < 16) {
      float tot = 0.f;
#pragma unroll
      for (int w = 0; w < 8; w++) tot += wred[w][row16];
      invr[row16] = 1.0f / tot;
    }
  }

  // ---- PV on unnormalized bf16 e: wave covers its 256-col slice ----
  f32x4 accd[4] = {};
#pragma unroll 2
  for (int jj = 0; jj < 8; jj++) {
    int jb = wid * 256 + jj * 32;
    s16x8 af = *(const s16x8*)&Sbf[(size_t)lc * SROWB + jb + lg * 8];
    __builtin_amdgcn_s_setprio(1);
#pragma unroll
    for (int f = 0; f < 4; f++) {
      s16x8 bv = *(const s16x8*)&vb[(size_t)(f * 16 + lc) * NSEQ + jb + lg * 8];
      accd[f] = __builtin_amdgcn_mfma_f32_16x16x32_bf16(af, bv, accd[f], 0, 0, 0);
    }
    __builtin_amdgcn_s_setprio(0);
  }

  // ---- stash Sbf rows 0..3 (to be clobbered by part alias) in registers ----
  // mapping == attn-store mapping: row = tid>>5, cols (tid&31)*8 + k*256
  s16x8 stash[8];
  const int srow = tid >> 5;         // 0..15; stash only used when <4 (tid<128)
  const int scc = (tid & 31) * 8;
  if (tid < 128) {
#pragma unroll
    for (int k = 0; k < 8; k++)
      stash[k] = *(const s16x8*)&Sbf[(size_t)srow * SROWB + scc + k * 256];
  }
  __syncthreads();   // PV + stash reads of Sbf complete; part may alias now

  // staged cross-wave reduce: waves 0-3 write, waves 4-7 accumulate
  if (wid < 4) {
#pragma unroll
    for (int f = 0; f < 4; f++)
#pragma unroll
      for (int r = 0; r < 4; r++)
        part[((size_t)wid * 16 + lg * 4 + r) * 64 + f * 16 + lc] = accd[f][r];
  }
  __syncthreads();
  if (wid >= 4) {
#pragma unroll
    for (int f = 0; f < 4; f++)
#pragma unroll
      for (int r = 0; r < 4; r++)
        part[((size_t)(wid - 4) * 16 + lg * 4 + r) * 64 + f * 16 + lc] += accd[f][r];
  }
  __syncthreads();

  // ---- ctx reduce, normalize, bf16, write ctx [B][N][H*64] ----
  if (tid < 256) {
    const int oi = tid >> 4;
    const int d0 = (tid & 15) * 4;
    float4 p0 = *(float4*)&part[((size_t)0 * 16 + oi) * 64 + d0];
    float4 p1 = *(float4*)&part[((size_t)1 * 16 + oi) * 64 + d0];
    float4 p2 = *(float4*)&part[((size_t)2 * 16 + oi) * 64 + d0];
    float4 p3 = *(float4*)&part[((size_t)3 * 16 + oi) * 64 + d0];
    float iv = invr[oi];
    float4 tot;
    tot.x = (p0.x + p1.x + p2.x + p3.x) * iv;
    tot.y = (p0.y + p1.y + p2.y + p3.y) * iv;
    tot.z = (p0.z + p1.z + p2.z + p3.z) * iv;
    tot.w = (p0.w + p1.w + p2.w + p3.w) * iv;
    ushort4 o;
    o.x = f2bf(tot.x); o.y = f2bf(tot.y); o.z = f2bf(tot.z); o.w = f2bf(tot.w);
    *(ushort4*)&ctx[(size_t)(b * NSEQ + i0 + oi) * DMODEL + h * HD + d0] = o;
  }

  // ---- attn store LAST: no loads behind these stores ----
  // rows 0..3 (tid<128) from stash regs; rows 4..15 from LDS (untouched).
  {
    const float inv = invr[srow];
    float* arow = attn_g + ((size_t)(b * NHEADS + h) * NSEQ + i0 + srow) * NSEQ + scc;
#pragma unroll
    for (int k = 0; k < 8; k++) {
      s16x8 ev;
      if (tid < 128) ev = stash[k];
      else ev = *(const s16x8*)&Sbf[(size_t)srow * SROWB + scc + k * 256];
      f32x4 f0, f1;
      f0[0] = bf2f((unsigned short)ev[0]) * inv;
      f0[1] = bf2f((unsigned short)ev[1]) * inv;
      f0[2] = bf2f((unsigned short)ev[2]) * inv;
      f0[3] = bf2f((unsigned short)ev[3]) * inv;
      f1[0] = bf2f((unsigned short)ev[4]) * inv;
      f1[1] = bf2f((unsigned short)ev[5]) * inv;
      f1[2] = bf2f((unsigned short)ev[6]) * inv;
      f1[3] = bf2f((unsigned short)ev[7]) * inv;
      *(f32x4*)&arow[k * 256] = f0;
      *(f32x4*)&arow[k * 256 + 4] = f1;
    }
  }
}

extern "C" void kernel_launch(void* const* d_in, const int* in_sizes, int n_in,
                              void* d_out, int out_size, void* d_ws, size_t ws_size,
                              hipStream_t stream) {
  const float* src     = (const float*)d_in[0];
  const float* sin_src = (const float*)d_in[1];
  const float* cos_src = (const float*)d_in[2];
  const float* tgt     = (const float*)d_in[3];
  const float* sin_tgt = (const float*)d_in[4];
  const float* cos_tgt = (const float*)d_in[5];
  const float* wq      = (const float*)d_in[6];
  const float* wkv     = (const float*)d_in[7];
  const float* wout    = (const float*)d_in[8];
  const float* bout    = (const float*)d_in[9];

  if (ws_size < (size_t)109051904) return;

  uint8_t* w = (uint8_t*)d_ws;
  unsigned short* tgt_bf = (unsigned short*)(w + 0);
  unsigned short* src_bf = (unsigned short*)(w + 8388608);
  unsigned short* wq_t   = (unsigned short*)(w + 16777216);
  unsigned short* wkv_t  = (unsigned short*)(w + 18874368);
  unsigned short* wout_t = (unsigned short*)(w + 23068672);
  float*          q_ws   = (float*)(w + 25165824);
  float*          kv_ws  = (float*)(w + 41943040);
  unsigned short* qhb    = (unsigned short*)(w + 75497472);
  unsigned short* khb    = (unsigned short*)(w + 83886080);
  unsigned short* vtb    = (unsigned short*)(w + 92274688);
  unsigned short* ctx    = (unsigned short*)(w + 100663296);

  float* out_p  = (float*)d_out;
  float* attn_p = out_p + (size_t)NB * NSEQ * DMODEL;

  k_convert<<<4096, 256, 0, stream>>>(tgt, tgt_bf, 1048576);
  k_convert<<<4096, 256, 0, stream>>>(src, src_bf, 1048576);
  k_transpose<<<dim3(16, 16), 256, 0, stream>>>(wq,   wq_t,   1024, 1024);
  k_transpose<<<dim3(32, 16), 256, 0, stream>>>(wkv,  wkv_t,  1024, 2048);
  k_transpose<<<dim3(16, 16), 256, 0, stream>>>(wout, wout_t, 1024, 1024);

  k_gemm<<<dim3(8, 32),  256, 0, stream>>>(tgt_bf, wq_t,  q_ws,  nullptr, 4096, 1024, 1024);
  k_gemm<<<dim3(16, 32), 256, 0, stream>>>(src_bf, wkv_t, kv_ws, nullptr, 4096, 2048, 1024);

  k_rope<<<8192, 256, 0, stream>>>(q_ws, 1024, sin_tgt, cos_tgt, qhb);
  k_rope<<<8192, 256, 0, stream>>>(kv_ws, 2048, sin_src, cos_src, khb);
  k_vtrans<<<dim3(32, 16, 2), 256, 0, stream>>>(kv_ws, vtb);

  k_attn<<<dim3(128, 16, 2), 512, 0, stream>>>(qhb, khb, vtb, attn_p, ctx);

  k_gemm<<<dim3(8, 32), 256, 0, stream>>>(ctx, wout_t, out_p, bout, 4096, 1024, 1024);
}

// Round 7
// 456.965 us; speedup vs baseline: 1.0305x; 1.0305x over previous
//
#include <hip/hip_runtime.h>
#include <hip/hip_bf16.h>
#include <cstdint>
#include <cstddef>

#define NB 2
#define NSEQ 2048
#define NHEADS 16
#define HD 64
#define DMODEL 1024
#define SCALEF 0.125f

typedef __attribute__((ext_vector_type(4))) float f32x4;
typedef __attribute__((ext_vector_type(8))) short s16x8;

__device__ __forceinline__ unsigned short f2bf(float f) {
  union { float f; unsigned u; } v; v.f = f;
  unsigned u = v.u;
  return (unsigned short)((u + 0x7fffu + ((u >> 16) & 1u)) >> 16);
}
__device__ __forceinline__ float bf2f(unsigned short s) {
  union { unsigned u; float f; } v; v.u = ((unsigned)s) << 16;
  return v.f;
}

// ---------- fp32 -> bf16 straight convert (float4 vectorized) ----------
__global__ void k_convert(const float* __restrict__ in, unsigned short* __restrict__ out, int n4) {
  int i = blockIdx.x * blockDim.x + threadIdx.x;
  if (i >= n4) return;
  float4 v = ((const float4*)in)[i];
  ushort4 o;
  o.x = f2bf(v.x); o.y = f2bf(v.y); o.z = f2bf(v.z); o.w = f2bf(v.w);
  ((ushort4*)out)[i] = o;
}

// ---------- w [K][N] fp32 -> wt [N][K] bf16 (LDS-tiled transpose) ----------
__global__ void k_transpose(const float* __restrict__ w, unsigned short* __restrict__ wt, int K, int N) {
  __shared__ float t[64][65];
  int n0 = blockIdx.x * 64, k0 = blockIdx.y * 64;
  int c = threadIdx.x & 63, rb = threadIdx.x >> 6;
#pragma unroll
  for (int rr = 0; rr < 16; rr++) {
    int k = rb * 16 + rr;
    t[c][k] = w[(size_t)(k0 + k) * N + n0 + c];
  }
  __syncthreads();
#pragma unroll
  for (int rr = 0; rr < 16; rr++) {
    int n = rb * 16 + rr;
    wt[(size_t)(n0 + n) * K + k0 + c] = f2bf(t[n][c]);
  }
}

// ---------- bf16 MFMA GEMM: C[M][N] = A[M][K] @ Bt[N][K]^T (+bias) ----------
#define GLD16(gp, lp) __builtin_amdgcn_global_load_lds( \
    (const __attribute__((address_space(1))) unsigned int*)(gp), \
    (__attribute__((address_space(3))) unsigned int*)(lp), 16, 0, 0)

__global__ __launch_bounds__(256) void k_gemm(const unsigned short* __restrict__ A,
                                              const unsigned short* __restrict__ Bt,
                                              float* __restrict__ C,
                                              const float* __restrict__ bias,
                                              int M, int N, int K) {
  __shared__ unsigned short As[128 * 32];
  __shared__ unsigned short Bs[128 * 32];
  const int tid = threadIdx.x;
  const int lane = tid & 63, wid = tid >> 6;
  const int m0 = blockIdx.y * 128, n0 = blockIdx.x * 128;
  const int wr = wid >> 1, wc = wid & 1;
  const int lr = lane >> 2, l4 = lane & 3;
  const int lc = lane & 15, lg = lane >> 4;

  const unsigned short* pa0 = A + (size_t)(m0 + wid * 32 + lr) * K + l4 * 8;
  const unsigned short* pa1 = pa0 + (size_t)16 * K;
  const unsigned short* pb0 = Bt + (size_t)(n0 + wid * 32 + lr) * K + l4 * 8;
  const unsigned short* pb1 = pb0 + (size_t)16 * K;

  f32x4 acc[4][4] = {};

  for (int kt = 0; kt < K; kt += 32) {
    GLD16(pa0 + kt, &As[wid * 1024]);
    GLD16(pa1 + kt, &As[wid * 1024 + 512]);
    GLD16(pb0 + kt, &Bs[wid * 1024]);
    GLD16(pb1 + kt, &Bs[wid * 1024 + 512]);
    __syncthreads();
    s16x8 af[4], bfr[4];
#pragma unroll
    for (int m = 0; m < 4; m++)
      af[m] = *(const s16x8*)&As[(wr * 64 + m * 16 + lc) * 32 + lg * 8];
#pragma unroll
    for (int n = 0; n < 4; n++)
      bfr[n] = *(const s16x8*)&Bs[(wc * 64 + n * 16 + lc) * 32 + lg * 8];
    __builtin_amdgcn_s_setprio(1);
#pragma unroll
    for (int m = 0; m < 4; m++)
#pragma unroll
      for (int n = 0; n < 4; n++)
        acc[m][n] = __builtin_amdgcn_mfma_f32_16x16x32_bf16(af[m], bfr[n], acc[m][n], 0, 0, 0);
    __builtin_amdgcn_s_setprio(0);
    __syncthreads();
  }

  float bv[4] = {0.f, 0.f, 0.f, 0.f};
  if (bias) {
#pragma unroll
    for (int n = 0; n < 4; n++) bv[n] = bias[n0 + wc * 64 + n * 16 + lc];
  }
#pragma unroll
  for (int m = 0; m < 4; m++) {
#pragma unroll
    for (int n = 0; n < 4; n++) {
      int col = n0 + wc * 64 + n * 16 + lc;
#pragma unroll
      for (int r = 0; r < 4; r++) {
        int row = m0 + wr * 64 + m * 16 + lg * 4 + r;
        C[(size_t)row * N + col] = acc[m][n][r] + bv[n];
      }
    }
  }
}

// ---------- RoPE + head-split relayout: [B][N][H*64] f32 -> [B][H][N][64] bf16 ----------
__global__ void k_rope(const float* __restrict__ src, int row_stride,
                       const float* __restrict__ sinp, const float* __restrict__ cosp,
                       unsigned short* __restrict__ dst) {
  int tid = blockIdx.x * 256 + threadIdx.x;
  int p = tid & 31;
  int h = (tid >> 5) & 15;
  int i = (tid >> 9) & 2047;
  int b = tid >> 20;
  int d = p * 2;
  float2 x = *(const float2*)(src + (size_t)(b * NSEQ + i) * row_stride + h * HD + d);
  float o0, o1;
  if (p < 16) {
    size_t sc = (size_t)(b * NSEQ + i) * 32 + d;
    float2 cc = *(const float2*)(cosp + sc);
    float2 ss = *(const float2*)(sinp + sc);
    o0 = x.x * cc.x - x.y * ss.x;
    o1 = x.y * cc.y + x.x * ss.y;
  } else { o0 = x.x; o1 = x.y; }
  size_t off = ((size_t)(b * NHEADS + h) * NSEQ + i) * HD + d;
  unsigned pack = (unsigned)f2bf(o0) | ((unsigned)f2bf(o1) << 16);
  *(unsigned*)(dst + off) = pack;
}

// ---------- v relayout+transpose: kv[B][N][2048](cols 1024..) -> vt [B][H][64][N] bf16 ----------
__global__ void k_vtrans(const float* __restrict__ kv, unsigned short* __restrict__ vt) {
  __shared__ float t[64][65];
  int i0 = blockIdx.x * 64;
  int h = blockIdx.y, b = blockIdx.z;
  int c = threadIdx.x & 63, rb = threadIdx.x >> 6;
#pragma unroll
  for (int rr = 0; rr < 16; rr++) {
    int il = rb * 16 + rr;
    t[il][c] = kv[(size_t)(b * NSEQ + i0 + il) * 2048 + 1024 + h * HD + c];
  }
  __syncthreads();
#pragma unroll
  for (int rr = 0; rr < 16; rr++) {
    int dd = rb * 16 + rr;
    vt[((size_t)(b * NHEADS + h) * HD + dd) * NSEQ + i0 + c] = f2bf(t[c][dd]);
  }
}

// ---------- fused attention v6: explicit load prefetch rings ----------
// Diagnosis r6: VGPR=52 compile serialized K/V loads (load->wait->mfma chains,
// ~700cy L3 latency each => ~45k cy/wave). Fix: 4-deep K prefetch ring and
// 2-deep V prefetch ring (static indices via full unroll) so each MFMA's
// s_waitcnt leaves 8+ younger loads in flight (counted-vmcnt pattern).
#define SROWB 2056
__global__ __launch_bounds__(512, 4) void k_attn(const unsigned short* __restrict__ qh,
                                                 const unsigned short* __restrict__ kh,
                                                 const unsigned short* __restrict__ vt,
                                                 float* __restrict__ attn_g,
                                                 unsigned short* __restrict__ ctx) {
  __shared__ unsigned short Sbf[16 * SROWB];   // 65,792 B (bf16 e-values)
  __shared__ float wred[8][16];                // per-wave partial row sums
  __shared__ float invr[16];
  float* part = (float*)Sbf;                   // aliased after stash: [4][16][64]

  const int tid = threadIdx.x;
  const int lane = tid & 63, wid = tid >> 6;   // wid 0..7
  const int i0 = blockIdx.x * 16;
  const int h = blockIdx.y, b = blockIdx.z;
  const int lc = lane & 15, lg = lane >> 4;

  const unsigned short* qb = qh + ((size_t)(b * NHEADS + h) * NSEQ + i0) * HD;
  const unsigned short* kb = kh + (size_t)(b * NHEADS + h) * NSEQ * HD;
  const unsigned short* vb = vt + (size_t)(b * NHEADS + h) * HD * NSEQ;

  // ---- QK^T fused with exp: wave covers cols [wid*256, wid*256+256) ----
  s16x8 aq0 = *(const s16x8*)&qb[lc * HD + lg * 8];
  s16x8 aq1 = *(const s16x8*)&qb[lc * HD + 32 + lg * 8];
  float psum[4] = {0.f, 0.f, 0.f, 0.f};

  // K prefetch ring, depth 4 (fully unrolled -> registers)
  const unsigned short* krow = kb + (size_t)(wid * 256 + lc) * HD + lg * 8;
  s16x8 kpre[4][2];
#pragma unroll
  for (int p = 0; p < 4; p++) {
    kpre[p][0] = *(const s16x8*)&krow[(size_t)(p * 16) * HD];
    kpre[p][1] = *(const s16x8*)&krow[(size_t)(p * 16) * HD + 32];
  }
#pragma unroll
  for (int jf = 0; jf < 16; jf++) {
    s16x8 b0 = kpre[jf & 3][0];
    s16x8 b1 = kpre[jf & 3][1];
    if (jf < 12) {
      kpre[jf & 3][0] = *(const s16x8*)&krow[(size_t)((jf + 4) * 16) * HD];
      kpre[jf & 3][1] = *(const s16x8*)&krow[(size_t)((jf + 4) * 16) * HD + 32];
    }
    int j = wid * 256 + jf * 16;
    f32x4 acc = {};
    acc = __builtin_amdgcn_mfma_f32_16x16x32_bf16(aq0, b0, acc, 0, 0, 0);
    acc = __builtin_amdgcn_mfma_f32_16x16x32_bf16(aq1, b1, acc, 0, 0, 0);
#pragma unroll
    for (int r = 0; r < 4; r++) {
      float e = __expf(acc[r] * SCALEF);       // no max-sub: |s| bounded ~6
      psum[r] += e;
      Sbf[(size_t)(lg * 4 + r) * SROWB + j + lc] = f2bf(e);
    }
  }
  // row-sum: reduce over the 16 lanes sharing lg, then stage per-wave
#pragma unroll
  for (int off = 1; off <= 8; off <<= 1)
#pragma unroll
    for (int r = 0; r < 4; r++) psum[r] += __shfl_xor(psum[r], off);
  if (lc == 0) {
#pragma unroll
    for (int r = 0; r < 4; r++) wred[wid][lg * 4 + r] = psum[r];
  }
  __syncthreads();

  // ---- per-row inverse sum ----
  if (tid < 16) {
    float tot = 0.f;
#pragma unroll
    for (int w = 0; w < 8; w++) tot += wred[w][tid];
    invr[tid] = 1.0f / tot;
  }

  // ---- PV on unnormalized bf16 e: wave covers its 256-col slice ----
  // V prefetch ring, depth 2
  const unsigned short* vrow = vb + (size_t)lc * NSEQ + wid * 256 + lg * 8;
  f32x4 accd[4] = {};
  s16x8 vpre[2][4];
#pragma unroll
  for (int f = 0; f < 4; f++)
    vpre[0][f] = *(const s16x8*)&vrow[(size_t)(f * 16) * NSEQ];
#pragma unroll
  for (int jj = 0; jj < 8; jj++) {
    int jb = wid * 256 + jj * 32;
    s16x8 af = *(const s16x8*)&Sbf[(size_t)lc * SROWB + jb + lg * 8];
    if (jj < 7) {
#pragma unroll
      for (int f = 0; f < 4; f++)
        vpre[(jj + 1) & 1][f] = *(const s16x8*)&vrow[(size_t)(f * 16) * NSEQ + (jj + 1) * 32];
    }
    __builtin_amdgcn_s_setprio(1);
#pragma unroll
    for (int f = 0; f < 4; f++)
      accd[f] = __builtin_amdgcn_mfma_f32_16x16x32_bf16(af, vpre[jj & 1][f], accd[f], 0, 0, 0);
    __builtin_amdgcn_s_setprio(0);
  }

  // ---- stash Sbf rows 0..3 (to be clobbered by part alias) in registers ----
  s16x8 stash[8];
  const int srow = tid >> 5;         // 0..15; stash only used when tid<128
  const int scc = (tid & 31) * 8;
  if (tid < 128) {
#pragma unroll
    for (int k = 0; k < 8; k++)
      stash[k] = *(const s16x8*)&Sbf[(size_t)srow * SROWB + scc + k * 256];
  }
  __syncthreads();   // PV + stash reads of Sbf complete; part may alias now

  // staged cross-wave reduce: waves 0-3 write, waves 4-7 accumulate
  if (wid < 4) {
#pragma unroll
    for (int f = 0; f < 4; f++)
#pragma unroll
      for (int r = 0; r < 4; r++)
        part[((size_t)wid * 16 + lg * 4 + r) * 64 + f * 16 + lc] = accd[f][r];
  }
  __syncthreads();
  if (wid >= 4) {
#pragma unroll
    for (int f = 0; f < 4; f++)
#pragma unroll
      for (int r = 0; r < 4; r++)
        part[((size_t)(wid - 4) * 16 + lg * 4 + r) * 64 + f * 16 + lc] += accd[f][r];
  }
  __syncthreads();

  // ---- ctx reduce, normalize, bf16, write ctx [B][N][H*64] ----
  if (tid < 256) {
    const int oi = tid >> 4;
    const int d0 = (tid & 15) * 4;
    float4 p0 = *(float4*)&part[((size_t)0 * 16 + oi) * 64 + d0];
    float4 p1 = *(float4*)&part[((size_t)1 * 16 + oi) * 64 + d0];
    float4 p2 = *(float4*)&part[((size_t)2 * 16 + oi) * 64 + d0];
    float4 p3 = *(float4*)&part[((size_t)3 * 16 + oi) * 64 + d0];
    float iv = invr[oi];
    float4 tot;
    tot.x = (p0.x + p1.x + p2.x + p3.x) * iv;
    tot.y = (p0.y + p1.y + p2.y + p3.y) * iv;
    tot.z = (p0.z + p1.z + p2.z + p3.z) * iv;
    tot.w = (p0.w + p1.w + p2.w + p3.w) * iv;
    ushort4 o;
    o.x = f2bf(tot.x); o.y = f2bf(tot.y); o.z = f2bf(tot.z); o.w = f2bf(tot.w);
    *(ushort4*)&ctx[(size_t)(b * NSEQ + i0 + oi) * DMODEL + h * HD + d0] = o;
  }

  // ---- attn store LAST ----
  {
    const float inv = invr[srow];
    float* arow = attn_g + ((size_t)(b * NHEADS + h) * NSEQ + i0 + srow) * NSEQ + scc;
#pragma unroll
    for (int k = 0; k < 8; k++) {
      s16x8 ev;
      if (tid < 128) ev = stash[k];
      else ev = *(const s16x8*)&Sbf[(size_t)srow * SROWB + scc + k * 256];
      f32x4 f0, f1;
      f0[0] = bf2f((unsigned short)ev[0]) * inv;
      f0[1] = bf2f((unsigned short)ev[1]) * inv;
      f0[2] = bf2f((unsigned short)ev[2]) * inv;
      f0[3] = bf2f((unsigned short)ev[3]) * inv;
      f1[0] = bf2f((unsigned short)ev[4]) * inv;
      f1[1] = bf2f((unsigned short)ev[5]) * inv;
      f1[2] = bf2f((unsigned short)ev[6]) * inv;
      f1[3] = bf2f((unsigned short)ev[7]) * inv;
      *(f32x4*)&arow[k * 256] = f0;
      *(f32x4*)&arow[k * 256 + 4] = f1;
    }
  }
}

extern "C" void kernel_launch(void* const* d_in, const int* in_sizes, int n_in,
                              void* d_out, int out_size, void* d_ws, size_t ws_size,
                              hipStream_t stream) {
  const float* src     = (const float*)d_in[0];
  const float* sin_src = (const float*)d_in[1];
  const float* cos_src = (const float*)d_in[2];
  const float* tgt     = (const float*)d_in[3];
  const float* sin_tgt = (const float*)d_in[4];
  const float* cos_tgt = (const float*)d_in[5];
  const float* wq      = (const float*)d_in[6];
  const float* wkv     = (const float*)d_in[7];
  const float* wout    = (const float*)d_in[8];
  const float* bout    = (const float*)d_in[9];

  if (ws_size < (size_t)109051904) return;

  uint8_t* w = (uint8_t*)d_ws;
  unsigned short* tgt_bf = (unsigned short*)(w + 0);
  unsigned short* src_bf = (unsigned short*)(w + 8388608);
  unsigned short* wq_t   = (unsigned short*)(w + 16777216);
  unsigned short* wkv_t  = (unsigned short*)(w + 18874368);
  unsigned short* wout_t = (unsigned short*)(w + 23068672);
  float*          q_ws   = (float*)(w + 25165824);
  float*          kv_ws  = (float*)(w + 41943040);
  unsigned short* qhb    = (unsigned short*)(w + 75497472);
  unsigned short* khb    = (unsigned short*)(w + 83886080);
  unsigned short* vtb    = (unsigned short*)(w + 92274688);
  unsigned short* ctx    = (unsigned short*)(w + 100663296);

  float* out_p  = (float*)d_out;
  float* attn_p = out_p + (size_t)NB * NSEQ * DMODEL;

  k_convert<<<4096, 256, 0, stream>>>(tgt, tgt_bf, 1048576);
  k_convert<<<4096, 256, 0, stream>>>(src, src_bf, 1048576);
  k_transpose<<<dim3(16, 16), 256, 0, stream>>>(wq,   wq_t,   1024, 1024);
  k_transpose<<<dim3(32, 16), 256, 0, stream>>>(wkv,  wkv_t,  1024, 2048);
  k_transpose<<<dim3(16, 16), 256, 0, stream>>>(wout, wout_t, 1024, 1024);

  k_gemm<<<dim3(8, 32),  256, 0, stream>>>(tgt_bf, wq_t,  q_ws,  nullptr, 4096, 1024, 1024);
  k_gemm<<<dim3(16, 32), 256, 0, stream>>>(src_bf, wkv_t, kv_ws, nullptr, 4096, 2048, 1024);

  k_rope<<<8192, 256, 0, stream>>>(q_ws, 1024, sin_tgt, cos_tgt, qhb);
  k_rope<<<8192, 256, 0, stream>>>(kv_ws, 2048, sin_src, cos_src, khb);
  k_vtrans<<<dim3(32, 16, 2), 256, 0, stream>>>(kv_ws, vtb);

  k_attn<<<dim3(128, 16, 2), 512, 0, stream>>>(qhb, khb, vtb, attn_p, ctx);

  k_gemm<<<dim3(8, 32), 256, 0, stream>>>(ctx, wout_t, out_p, bout, 4096, 1024, 1024);
}

// Round 8
// 390.862 us; speedup vs baseline: 1.2048x; 1.1691x over previous
//
#include <hip/hip_runtime.h>
#include <hip/hip_bf16.h>
#include <cstdint>
#include <cstddef>

#define NB 2
#define NSEQ 2048
#define NHEADS 16
#define HD 64
#define DMODEL 1024
#define SCALEF 0.125f

typedef __attribute__((ext_vector_type(4))) float f32x4;
typedef __attribute__((ext_vector_type(8))) short s16x8;

__device__ __forceinline__ unsigned short f2bf(float f) {
  union { float f; unsigned u; } v; v.f = f;
  unsigned u = v.u;
  return (unsigned short)((u + 0x7fffu + ((u >> 16) & 1u)) >> 16);
}
__device__ __forceinline__ float bf2f(unsigned short s) {
  union { unsigned u; float f; } v; v.u = ((unsigned)s) << 16;
  return v.f;
}

// ---------- fp32 -> bf16 straight convert (float4 vectorized) ----------
__global__ void k_convert(const float* __restrict__ in, unsigned short* __restrict__ out, int n4) {
  int i = blockIdx.x * blockDim.x + threadIdx.x;
  if (i >= n4) return;
  float4 v = ((const float4*)in)[i];
  ushort4 o;
  o.x = f2bf(v.x); o.y = f2bf(v.y); o.z = f2bf(v.z); o.w = f2bf(v.w);
  ((ushort4*)out)[i] = o;
}

// ---------- w [K][N] fp32 -> wt [N][K] bf16 (LDS-tiled transpose) ----------
__global__ void k_transpose(const float* __restrict__ w, unsigned short* __restrict__ wt, int K, int N) {
  __shared__ float t[64][65];
  int n0 = blockIdx.x * 64, k0 = blockIdx.y * 64;
  int c = threadIdx.x & 63, rb = threadIdx.x >> 6;
#pragma unroll
  for (int rr = 0; rr < 16; rr++) {
    int k = rb * 16 + rr;
    t[c][k] = w[(size_t)(k0 + k) * N + n0 + c];
  }
  __syncthreads();
#pragma unroll
  for (int rr = 0; rr < 16; rr++) {
    int n = rb * 16 + rr;
    wt[(size_t)(n0 + n) * K + k0 + c] = f2bf(t[n][c]);
  }
}

// ---------- bf16 MFMA GEMM: C[M][N] = A[M][K] @ Bt[N][K]^T (+bias) ----------
#define GLD16(gp, lp) __builtin_amdgcn_global_load_lds( \
    (const __attribute__((address_space(1))) unsigned int*)(gp), \
    (__attribute__((address_space(3))) unsigned int*)(lp), 16, 0, 0)

__global__ __launch_bounds__(256) void k_gemm(const unsigned short* __restrict__ A,
                                              const unsigned short* __restrict__ Bt,
                                              float* __restrict__ C,
                                              const float* __restrict__ bias,
                                              int M, int N, int K) {
  __shared__ unsigned short As[128 * 32];
  __shared__ unsigned short Bs[128 * 32];
  const int tid = threadIdx.x;
  const int lane = tid & 63, wid = tid >> 6;
  const int m0 = blockIdx.y * 128, n0 = blockIdx.x * 128;
  const int wr = wid >> 1, wc = wid & 1;
  const int lr = lane >> 2, l4 = lane & 3;
  const int lc = lane & 15, lg = lane >> 4;

  const unsigned short* pa0 = A + (size_t)(m0 + wid * 32 + lr) * K + l4 * 8;
  const unsigned short* pa1 = pa0 + (size_t)16 * K;
  const unsigned short* pb0 = Bt + (size_t)(n0 + wid * 32 + lr) * K + l4 * 8;
  const unsigned short* pb1 = pb0 + (size_t)16 * K;

  f32x4 acc[4][4] = {};

  for (int kt = 0; kt < K; kt += 32) {
    GLD16(pa0 + kt, &As[wid * 1024]);
    GLD16(pa1 + kt, &As[wid * 1024 + 512]);
    GLD16(pb0 + kt, &Bs[wid * 1024]);
    GLD16(pb1 + kt, &Bs[wid * 1024 + 512]);
    __syncthreads();
    s16x8 af[4], bfr[4];
#pragma unroll
    for (int m = 0; m < 4; m++)
      af[m] = *(const s16x8*)&As[(wr * 64 + m * 16 + lc) * 32 + lg * 8];
#pragma unroll
    for (int n = 0; n < 4; n++)
      bfr[n] = *(const s16x8*)&Bs[(wc * 64 + n * 16 + lc) * 32 + lg * 8];
    __builtin_amdgcn_s_setprio(1);
#pragma unroll
    for (int m = 0; m < 4; m++)
#pragma unroll
      for (int n = 0; n < 4; n++)
        acc[m][n] = __builtin_amdgcn_mfma_f32_16x16x32_bf16(af[m], bfr[n], acc[m][n], 0, 0, 0);
    __builtin_amdgcn_s_setprio(0);
    __syncthreads();
  }

  float bv[4] = {0.f, 0.f, 0.f, 0.f};
  if (bias) {
#pragma unroll
    for (int n = 0; n < 4; n++) bv[n] = bias[n0 + wc * 64 + n * 16 + lc];
  }
#pragma unroll
  for (int m = 0; m < 4; m++) {
#pragma unroll
    for (int n = 0; n < 4; n++) {
      int col = n0 + wc * 64 + n * 16 + lc;
#pragma unroll
      for (int r = 0; r < 4; r++) {
        int row = m0 + wr * 64 + m * 16 + lg * 4 + r;
        C[(size_t)row * N + col] = acc[m][n][r] + bv[n];
      }
    }
  }
}

// ---------- RoPE + head-split relayout: [B][N][H*64] f32 -> [B][H][N][64] bf16 ----------
__global__ void k_rope(const float* __restrict__ src, int row_stride,
                       const float* __restrict__ sinp, const float* __restrict__ cosp,
                       unsigned short* __restrict__ dst) {
  int tid = blockIdx.x * 256 + threadIdx.x;
  int p = tid & 31;
  int h = (tid >> 5) & 15;
  int i = (tid >> 9) & 2047;
  int b = tid >> 20;
  int d = p * 2;
  float2 x = *(const float2*)(src + (size_t)(b * NSEQ + i) * row_stride + h * HD + d);
  float o0, o1;
  if (p < 16) {
    size_t sc = (size_t)(b * NSEQ + i) * 32 + d;
    float2 cc = *(const float2*)(cosp + sc);
    float2 ss = *(const float2*)(sinp + sc);
    o0 = x.x * cc.x - x.y * ss.x;
    o1 = x.y * cc.y + x.x * ss.y;
  } else { o0 = x.x; o1 = x.y; }
  size_t off = ((size_t)(b * NHEADS + h) * NSEQ + i) * HD + d;
  unsigned pack = (unsigned)f2bf(o0) | ((unsigned)f2bf(o1) << 16);
  *(unsigned*)(dst + off) = pack;
}

// ---------- v relayout+transpose: kv[B][N][2048](cols 1024..) -> vt [B][H][64][N] bf16 ----------
__global__ void k_vtrans(const float* __restrict__ kv, unsigned short* __restrict__ vt) {
  __shared__ float t[64][65];
  int i0 = blockIdx.x * 64;
  int h = blockIdx.y, b = blockIdx.z;
  int c = threadIdx.x & 63, rb = threadIdx.x >> 6;
#pragma unroll
  for (int rr = 0; rr < 16; rr++) {
    int il = rb * 16 + rr;
    t[il][c] = kv[(size_t)(b * NSEQ + i0 + il) * 2048 + 1024 + h * HD + c];
  }
  __syncthreads();
#pragma unroll
  for (int rr = 0; rr < 16; rr++) {
    int dd = rb * 16 + rr;
    vt[((size_t)(b * NHEADS + h) * HD + dd) * NSEQ + i0 + c] = f2bf(t[c][dd]);
  }
}

// ---------- fused attention v7: QBLK=32 (2x arithmetic intensity) ----------
// Diagnosis r7: per-block K+V re-read (512KB/block, 2.1GB total through
// L1/L2) at ~8 TB/s aggregate is the binding resource; schedule fixes were
// null. Fix: 32 q-rows/block halves read traffic per output. 1024 thr
// (16 waves x 128 cols), LDS Sbf[32][2056] bf16 = 131.6KB, 1 block/CU
// (same 4 waves/SIMD as before). attn store precedes the part alias.
#define QBLK 32
#define SROWB 2056
__global__ __launch_bounds__(1024, 4) void k_attn(const unsigned short* __restrict__ qh,
                                                  const unsigned short* __restrict__ kh,
                                                  const unsigned short* __restrict__ vt,
                                                  float* __restrict__ attn_g,
                                                  unsigned short* __restrict__ ctx) {
  __shared__ unsigned short Sbf[QBLK * SROWB];   // 131,584 B (bf16 e-values)
  __shared__ float wred[16][32];
  __shared__ float invr[32];
  float* part = (float*)Sbf;                     // aliased after attn store: [8][32][64]

  const int tid = threadIdx.x;
  const int lane = tid & 63, wid = tid >> 6;     // wid 0..15
  const int i0 = blockIdx.x * QBLK;
  const int h = blockIdx.y, b = blockIdx.z;
  const int lc = lane & 15, lg = lane >> 4;
  const int wcb = wid * 128;                     // wave's 128-col slice

  const unsigned short* qb = qh + ((size_t)(b * NHEADS + h) * NSEQ + i0) * HD;
  const unsigned short* kb = kh + (size_t)(b * NHEADS + h) * NSEQ * HD;
  const unsigned short* vb = vt + (size_t)(b * NHEADS + h) * HD * NSEQ;

  // ---- QK^T fused with exp: 2 row-groups of 16, wave covers 128 cols ----
  s16x8 aq[2][2];
#pragma unroll
  for (int rg = 0; rg < 2; rg++) {
    aq[rg][0] = *(const s16x8*)&qb[(rg * 16 + lc) * HD + lg * 8];
    aq[rg][1] = *(const s16x8*)&qb[(rg * 16 + lc) * HD + 32 + lg * 8];
  }
  float psum[2][4] = {};
  const unsigned short* krow = kb + (size_t)(wcb + lc) * HD + lg * 8;
  s16x8 kp[2][2];
  kp[0][0] = *(const s16x8*)&krow[0];
  kp[0][1] = *(const s16x8*)&krow[32];
#pragma unroll
  for (int jf = 0; jf < 8; jf++) {
    if (jf < 7) {
      kp[(jf + 1) & 1][0] = *(const s16x8*)&krow[(size_t)((jf + 1) * 16) * HD];
      kp[(jf + 1) & 1][1] = *(const s16x8*)&krow[(size_t)((jf + 1) * 16) * HD + 32];
    }
    int j = wcb + jf * 16;
#pragma unroll
    for (int rg = 0; rg < 2; rg++) {
      f32x4 acc = {};
      acc = __builtin_amdgcn_mfma_f32_16x16x32_bf16(aq[rg][0], kp[jf & 1][0], acc, 0, 0, 0);
      acc = __builtin_amdgcn_mfma_f32_16x16x32_bf16(aq[rg][1], kp[jf & 1][1], acc, 0, 0, 0);
#pragma unroll
      for (int r = 0; r < 4; r++) {
        float e = __expf(acc[r] * SCALEF);       // no max-sub: |s| bounded ~6
        psum[rg][r] += e;
        Sbf[(size_t)(rg * 16 + lg * 4 + r) * SROWB + j + lc] = f2bf(e);
      }
    }
  }
  // row-sum: reduce over the 16 lanes sharing lg, then stage per-wave
#pragma unroll
  for (int off = 1; off <= 8; off <<= 1)
#pragma unroll
    for (int rg = 0; rg < 2; rg++)
#pragma unroll
      for (int r = 0; r < 4; r++) psum[rg][r] += __shfl_xor(psum[rg][r], off);
  if (lc == 0) {
#pragma unroll
    for (int rg = 0; rg < 2; rg++)
#pragma unroll
      for (int r = 0; r < 4; r++) wred[wid][rg * 16 + lg * 4 + r] = psum[rg][r];
  }
  __syncthreads();
  if (tid < 32) {
    float tot = 0.f;
#pragma unroll
    for (int w = 0; w < 16; w++) tot += wred[w][tid];
    invr[tid] = 1.0f / tot;
  }

  // ---- PV on unnormalized bf16 e (wave-local Sbf slice; no barrier needed) ----
  f32x4 accd[2][4] = {};
  const unsigned short* vrow = vb + (size_t)lc * NSEQ + wcb + lg * 8;
  s16x8 vp[2][4];
#pragma unroll
  for (int f = 0; f < 4; f++)
    vp[0][f] = *(const s16x8*)&vrow[(size_t)(f * 16) * NSEQ];
#pragma unroll
  for (int jj = 0; jj < 4; jj++) {
    if (jj < 3) {
#pragma unroll
      for (int f = 0; f < 4; f++)
        vp[(jj + 1) & 1][f] = *(const s16x8*)&vrow[(size_t)(f * 16) * NSEQ + (jj + 1) * 32];
    }
    int jb = wcb + jj * 32;
    s16x8 af0 = *(const s16x8*)&Sbf[(size_t)lc * SROWB + jb + lg * 8];
    __builtin_amdgcn_s_setprio(1);
#pragma unroll
    for (int f = 0; f < 4; f++)
      accd[0][f] = __builtin_amdgcn_mfma_f32_16x16x32_bf16(af0, vp[jj & 1][f], accd[0][f], 0, 0, 0);
    __builtin_amdgcn_s_setprio(0);
    s16x8 af1 = *(const s16x8*)&Sbf[(size_t)(16 + lc) * SROWB + jb + lg * 8];
    __builtin_amdgcn_s_setprio(1);
#pragma unroll
    for (int f = 0; f < 4; f++)
      accd[1][f] = __builtin_amdgcn_mfma_f32_16x16x32_bf16(af1, vp[jj & 1][f], accd[1][f], 0, 0, 0);
    __builtin_amdgcn_s_setprio(0);
  }
  __syncthreads();   // invr visible; all waves' QK^T writes settled

  // ---- attn store (before part alias): row = tid>>5, 64 cols/thread ----
  {
    const int srow = tid >> 5;
    const int scc = (tid & 31) * 8;
    const float inv = invr[srow];
    float* arow = attn_g + ((size_t)(b * NHEADS + h) * NSEQ + i0 + srow) * NSEQ + scc;
#pragma unroll
    for (int k = 0; k < 8; k++) {
      s16x8 ev = *(const s16x8*)&Sbf[(size_t)srow * SROWB + scc + k * 256];
      f32x4 f0, f1;
      f0[0] = bf2f((unsigned short)ev[0]) * inv;
      f0[1] = bf2f((unsigned short)ev[1]) * inv;
      f0[2] = bf2f((unsigned short)ev[2]) * inv;
      f0[3] = bf2f((unsigned short)ev[3]) * inv;
      f1[0] = bf2f((unsigned short)ev[4]) * inv;
      f1[1] = bf2f((unsigned short)ev[5]) * inv;
      f1[2] = bf2f((unsigned short)ev[6]) * inv;
      f1[3] = bf2f((unsigned short)ev[7]) * inv;
      *(f32x4*)&arow[k * 256] = f0;
      *(f32x4*)&arow[k * 256 + 4] = f1;
    }
  }
  __syncthreads();   // all attn LDS reads done; part may alias Sbf now

  // ---- staged cross-wave reduce: waves 0-7 write, 8-15 accumulate ----
  if (wid < 8) {
#pragma unroll
    for (int rg = 0; rg < 2; rg++)
#pragma unroll
      for (int f = 0; f < 4; f++)
#pragma unroll
        for (int r = 0; r < 4; r++)
          part[((size_t)wid * 32 + rg * 16 + lg * 4 + r) * 64 + f * 16 + lc] = accd[rg][f][r];
  }
  __syncthreads();
  if (wid >= 8) {
#pragma unroll
    for (int rg = 0; rg < 2; rg++)
#pragma unroll
      for (int f = 0; f < 4; f++)
#pragma unroll
        for (int r = 0; r < 4; r++)
          part[((size_t)(wid - 8) * 32 + rg * 16 + lg * 4 + r) * 64 + f * 16 + lc] += accd[rg][f][r];
  }
  __syncthreads();

  // ---- ctx reduce, normalize, bf16, write ctx [B][N][H*64] ----
  {
    const int oi = tid >> 5;          // 0..31
    const int d0 = (tid & 31) * 2;    // 0..62
    float s0 = 0.f, s1 = 0.f;
#pragma unroll
    for (int p = 0; p < 8; p++) {
      s0 += part[((size_t)p * 32 + oi) * 64 + d0];
      s1 += part[((size_t)p * 32 + oi) * 64 + d0 + 1];
    }
    float iv = invr[oi];
    ushort2 o;
    o.x = f2bf(s0 * iv);
    o.y = f2bf(s1 * iv);
    *(ushort2*)&ctx[(size_t)(b * NSEQ + i0 + oi) * DMODEL + h * HD + d0] = o;
  }
}

extern "C" void kernel_launch(void* const* d_in, const int* in_sizes, int n_in,
                              void* d_out, int out_size, void* d_ws, size_t ws_size,
                              hipStream_t stream) {
  const float* src     = (const float*)d_in[0];
  const float* sin_src = (const float*)d_in[1];
  const float* cos_src = (const float*)d_in[2];
  const float* tgt     = (const float*)d_in[3];
  const float* sin_tgt = (const float*)d_in[4];
  const float* cos_tgt = (const float*)d_in[5];
  const float* wq      = (const float*)d_in[6];
  const float* wkv     = (const float*)d_in[7];
  const float* wout    = (const float*)d_in[8];
  const float* bout    = (const float*)d_in[9];

  if (ws_size < (size_t)109051904) return;

  uint8_t* w = (uint8_t*)d_ws;
  unsigned short* tgt_bf = (unsigned short*)(w + 0);
  unsigned short* src_bf = (unsigned short*)(w + 8388608);
  unsigned short* wq_t   = (unsigned short*)(w + 16777216);
  unsigned short* wkv_t  = (unsigned short*)(w + 18874368);
  unsigned short* wout_t = (unsigned short*)(w + 23068672);
  float*          q_ws   = (float*)(w + 25165824);
  float*          kv_ws  = (float*)(w + 41943040);
  unsigned short* qhb    = (unsigned short*)(w + 75497472);
  unsigned short* khb    = (unsigned short*)(w + 83886080);
  unsigned short* vtb    = (unsigned short*)(w + 92274688);
  unsigned short* ctx    = (unsigned short*)(w + 100663296);

  float* out_p  = (float*)d_out;
  float* attn_p = out_p + (size_t)NB * NSEQ * DMODEL;

  k_convert<<<4096, 256, 0, stream>>>(tgt, tgt_bf, 1048576);
  k_convert<<<4096, 256, 0, stream>>>(src, src_bf, 1048576);
  k_transpose<<<dim3(16, 16), 256, 0, stream>>>(wq,   wq_t,   1024, 1024);
  k_transpose<<<dim3(32, 16), 256, 0, stream>>>(wkv,  wkv_t,  1024, 2048);
  k_transpose<<<dim3(16, 16), 256, 0, stream>>>(wout, wout_t, 1024, 1024);

  k_gemm<<<dim3(8, 32),  256, 0, stream>>>(tgt_bf, wq_t,  q_ws,  nullptr, 4096, 1024, 1024);
  k_gemm<<<dim3(16, 32), 256, 0, stream>>>(src_bf, wkv_t, kv_ws, nullptr, 4096, 2048, 1024);

  k_rope<<<8192, 256, 0, stream>>>(q_ws, 1024, sin_tgt, cos_tgt, qhb);
  k_rope<<<8192, 256, 0, stream>>>(kv_ws, 2048, sin_src, cos_src, khb);
  k_vtrans<<<dim3(32, 16, 2), 256, 0, stream>>>(kv_ws, vtb);

  k_attn<<<dim3(64, 16, 2), 1024, 0, stream>>>(qhb, khb, vtb, attn_p, ctx);

  k_gemm<<<dim3(8, 32), 256, 0, stream>>>(ctx, wout_t, out_p, bout, 4096, 1024, 1024);
}